// Round 7
// baseline (239.058 us; speedup 1.0000x reference)
//
#include <hip/hip_runtime.h>

typedef short short8 __attribute__((ext_vector_type(8)));
typedef float f32x4 __attribute__((ext_vector_type(4)));

#define CST 3072  // cat row stride (6*512 channels)

__device__ __forceinline__ float bf2f(short s) {
  unsigned u = ((unsigned)(unsigned short)s) << 16;
  return __builtin_bit_cast(float, u);
}
__device__ __forceinline__ short f2bf(float f) {
  unsigned u = __builtin_bit_cast(unsigned, f);
  u = (u + 0x7FFFu + ((u >> 16) & 1u)) >> 16;
  return (short)u;
}
__device__ __forceinline__ void gl16(const short* g, short* l) {
  __builtin_amdgcn_global_load_lds(
      (const __attribute__((address_space(1))) unsigned*)g,
      (__attribute__((address_space(3))) unsigned*)l, 16, 0, 0);
}

// ---- merged init: blocks <1024 do NCHW->NHWC bf16 transpose of x
// (vectorized short8 stores); blocks 1024..1791 scale_w->bf16 (8 elem/thr);
// 1792..4671 wdr reorder; 4672..4675 stats zero.
__global__ __launch_bounds__(256) void k_init(const float* __restrict__ x,
                                              const float* __restrict__ sw,
                                              const float* __restrict__ w1, const float* __restrict__ w2,
                                              const float* __restrict__ w3, const float* __restrict__ w4,
                                              const float* __restrict__ w5,
                                              short* __restrict__ cat,
                                              short* __restrict__ wbf, short* __restrict__ wdr,
                                              float* __restrict__ stats) {
  __shared__ float tile[64][65];
  int b = blockIdx.x;
  int t = threadIdx.x;
  if (b < 1024) {
    int cblk = b & 7, h = (b >> 3) & 63, n = b >> 9;
    int c0 = cblk * 64;
    int lw = t & 63, grp = t >> 6;
    const float* xp = x + (((size_t)n * 512 + c0) * 64 + h) * 64;
#pragma unroll
    for (int i = 0; i < 16; ++i) {
      int cl = grp * 16 + i;
      tile[cl][lw] = xp[(size_t)cl * 4096 + lw];
    }
    __syncthreads();
    // store: thread -> (channel octet c8 = t&7, w = t>>3 (+32)); short8 writes
    int c8 = t & 7, wq = t >> 3;
    size_t mbase = ((size_t)n * 64 + h) * 64;
#pragma unroll
    for (int it = 0; it < 2; ++it) {
      int w = wq + it * 32;
      short8 o;
#pragma unroll
      for (int j = 0; j < 8; ++j) o[j] = f2bf(tile[c8 * 8 + j][w]);
      *(short8*)(cat + (mbase + w) * CST + c0 + c8 * 8) = o;
    }
  } else if (b < 1792) {
    // scale_w -> bf16, 8 elements per thread
    int i8 = (b - 1024) * 256 + t;
    const float4* sp = (const float4*)(sw + (size_t)i8 * 8);
    float4 f0 = sp[0], f1 = sp[1];
    short8 o;
    o[0] = f2bf(f0.x); o[1] = f2bf(f0.y); o[2] = f2bf(f0.z); o[3] = f2bf(f0.w);
    o[4] = f2bf(f1.x); o[5] = f2bf(f1.y); o[6] = f2bf(f1.z); o[7] = f2bf(f1.w);
    *(short8*)(wbf + (size_t)i8 * 8) = o;
  } else if (b < 4672) {
    int j = (b - 1792) * 256 + t;
    int c = j & 511;
    int t2 = j >> 9;
    int oc = t2 & 31;
    int t3 = t2 >> 5;
    int tap = t3 % 9;
    int di = t3 / 9;
    float v = 0.f;
    if (oc < 27) {
      const float* wp = (di == 0) ? w1 : (di == 1) ? w2 : (di == 2) ? w3 : (di == 3) ? w4 : w5;
      v = wp[((oc * 512 + c) * 3 + tap / 3) * 3 + tap % 3];
    }
    wdr[j] = f2bf(v);
  } else {
    int idx = (b - 4672) * 256 + t;
    stats[idx] = 0.f;
  }
}

// ---- offset conv + softmax + corner-table build. [R4 form restored —
// R20's T14 async-STAGE restructure measured neutral-to-negative.]
// Block = 128 thr (2 waves) = one image row (n,h): 64 positions.
// Wave covers 32 positions (2 m-tiles sharing B-frags): 2 b128/pos/tap.
// K split in halves (kh): LDS = A 32 KB + B 16 KB = 48 KB -> 3 blocks/CU
// (fo buffer aliases As: written only after all MFMA reads, extra barrier).
// Swizzle: LDS slot (row,ch) holds source chunk ch^(row&7).
// C/D layout: row (m=position) = quad*4+reg, col (n=oc) = l15.
__global__ __launch_bounds__(128) void k_conv(const short* __restrict__ xsrc,
                                              const short* __restrict__ wdr_all,
                                              int* __restrict__ ctab) {
  __shared__ short As[64 * 256];   // 32 KB: 64 cols x 256 ch (kh half)
  __shared__ short Bs[32 * 256];   // 16 KB: 32 oc x 256 ch
  float (*fo)[32][33] = (float (*)[32][33])(void*)As;  // aliased: used post-MFMA
  int tid = threadIdx.x;
  int wave = tid >> 6, lane = tid & 63;
  int l15 = lane & 15, quad = lane >> 4;
  int b = blockIdx.x;
  int di = b >> 7;
  int loc = b & 127;
  const int DIL[5] = {1, 6, 12, 24, 36};
  int d = DIL[di];
  int rid = (loc & 7) * 16 + (loc >> 3);  // xcd-affine row id (0..127)
  int h = rid & 63, n = rid >> 6;         // block-uniform row
  f32x4 acc[2][2];
  f32x4 zz = {0.f, 0.f, 0.f, 0.f};
#pragma unroll
  for (int i = 0; i < 2; ++i)
#pragma unroll
    for (int j = 0; j < 2; ++j) acc[i][j] = zz;
  const short8 z8 = {0, 0, 0, 0, 0, 0, 0, 0};
  // per-lane staging source offsets (slot q = i*128 + tid)
  int aoff[16];
  int boff[8];
#pragma unroll
  for (int i = 0; i < 16; ++i) {
    int q = i * 128 + tid;
    int w = q >> 5, ch = q & 31;
    aoff[i] = w * CST + (ch ^ (w & 7)) * 8;
  }
#pragma unroll
  for (int i = 0; i < 8; ++i) {
    int q = i * 128 + tid;
    int oc = q >> 5, ch = q & 31;
    boff[i] = oc * 512 + (ch ^ (oc & 7)) * 8;
  }
  const short* wbase = wdr_all + (size_t)di * 9 * 32 * 512;
  int rowb = (n << 12);
#pragma unroll 1
  for (int kh = 0; kh < 2; ++kh) {
    int lastty = -1;
#pragma unroll
    for (int tap = 0; tap < 9; ++tap) {
      int ty = tap / 3, tx = tap % 3;
      int hh = h + (ty - 1) * d;
      if ((unsigned)hh >= 64u) continue;   // block-uniform skip
      __syncthreads();                     // prior LDS reads complete
      if (ty != lastty) {                  // stage full row hh (A), kh half
        const short* abase = xsrc + (size_t)(rowb + (hh << 6)) * CST + kh * 256;
#pragma unroll
        for (int i = 0; i < 16; ++i)
          gl16(abase + aoff[i], As + (i * 128 + wave * 64) * 8);
        lastty = ty;
      }
      {                                    // stage B tap, kh half
        const short* bbase = wbase + tap * 32 * 512 + kh * 256;
#pragma unroll
        for (int i = 0; i < 8; ++i)
          gl16(bbase + boff[i], Bs + (i * 128 + wave * 64) * 8);
      }
      __syncthreads();                     // gl16 drained
      int s0 = wave * 32 + (tx - 1) * d;   // col of (mt,l15): s0 + mt*16 + l15
#pragma unroll
      for (int ks = 0; ks < 8; ++ks) {
        int c = ks * 4 + quad;
        short8 a[2], bb[2];
#pragma unroll
        for (int mt = 0; mt < 2; ++mt) {
          int wp = s0 + mt * 16 + l15;
          bool ok = (unsigned)wp < 64u;
          int wc = ok ? wp : 0;
          short8 av = *(const short8*)(As + wc * 256 + (c ^ (wc & 7)) * 8);
          a[mt] = ok ? av : z8;
        }
#pragma unroll
        for (int ot = 0; ot < 2; ++ot) {
          int oc = ot * 16 + l15;
          bb[ot] = *(const short8*)(Bs + oc * 256 + (c ^ (oc & 7)) * 8);
        }
#pragma unroll
        for (int mt = 0; mt < 2; ++mt)
#pragma unroll
          for (int ot = 0; ot < 2; ++ot)
            acc[mt][ot] = __builtin_amdgcn_mfma_f32_16x16x32_bf16(a[mt], bb[ot], acc[mt][ot], 0, 0, 0);
      }
    }
  }
  __syncthreads();   // all waves done reading As before fo (aliased) is written
  // write fo: C row (quad*4+r) = position, C col (l15) = oc
#pragma unroll
  for (int mt = 0; mt < 2; ++mt)
#pragma unroll
    for (int ot = 0; ot < 2; ++ot)
#pragma unroll
      for (int r = 0; r < 4; ++r)
        fo[wave][mt * 16 + quad * 4 + r][ot * 16 + l15] = acc[mt][ot][r];
  __syncthreads();
  if (tid < 64) {   // softmax: one position per thread (wave0)
    int p = tid;
    float* fp = fo[p >> 5][p & 31];
    float mx = fp[0];
#pragma unroll
    for (int k = 1; k < 9; ++k) mx = fmaxf(mx, fp[k]);
    float s = 0.f, e[9];
#pragma unroll
    for (int k = 0; k < 9; ++k) { e[k] = __expf(fp[k] - mx); s += e[k]; }
    float inv = 1.f / s;
#pragma unroll
    for (int k = 0; k < 9; ++k) fp[k] = e[k] * inv;
  }
  __syncthreads();
  // corner table: 64 pos x 9 taps = 576 tasks over 128 threads, 5 rounds
#pragma unroll
  for (int rr = 0; rr < 5; ++rr) {
    int task = rr * 128 + tid;
    if (task < 576) {
      int p = task / 9;
      int k = task - p * 9;
      const float* fp = fo[p >> 5][p & 31];
      float f = fp[k];
      float dy = fp[9 + 2 * k];
      float dx = fp[10 + 2 * k];
      float ys = (float)(h + (k / 3 - 1) * d) + dy;
      float xs = (float)(p + (k % 3 - 1) * d) + dx;
      float y0f = floorf(ys), x0f = floorf(xs);
      float wy1 = ys - y0f, wx1 = xs - x0f;
      float wy0 = 1.f - wy1, wx0 = 1.f - wx1;
      int y0 = (int)y0f, x0 = (int)x0f;
      int4 ent;
      int* ep = (int*)&ent;
#pragma unroll
      for (int cy = 0; cy < 2; ++cy)
#pragma unroll
        for (int cx = 0; cx < 2; ++cx) {
          int yy = y0 + cy, xx = x0 + cx;
          bool v = ((unsigned)yy < 64u) && ((unsigned)xx < 64u);
          float wt = f * (cy ? wy1 : wy0) * (cx ? wx1 : wx0);
          int row = v ? (yy * 64 + xx) : 0;
          unsigned wb = v ? (unsigned)(unsigned short)f2bf(wt) : 0u;
          ep[cy * 2 + cx] = row | (int)(wb << 16);
        }
      int mm = rowb + (h << 6) + p;
      ((int4*)ctab)[((size_t)di * 8192 + mm) * 9 + k] = ent;
    }
  }
}

// ---- deform bilinear sample from precomputed corner table (R10/R12 form:
// one position per wave — measured local optimum; channel-split (R15) was
// 20% WORSE: two discontiguous 512B segments/instr + 2x ctab reads).
__global__ __launch_bounds__(256, 4) void k_samp(const short* __restrict__ xsrc,
                                                 short* __restrict__ cat,
                                                 const int* __restrict__ ctab) {
  int tid = threadIdx.x;
  int wv = __builtin_amdgcn_readfirstlane(tid >> 6);
  int lane = tid & 63;
  int b = blockIdx.x;
  int di = b >> 11;
  int loc = b & 2047;
  int m = (loc & 7) * 1024 + (loc >> 3) * 4 + wv;  // xcd*1024 + slab*4 + wave
  int n = m >> 12;
  const int4* tp = (const int4*)ctab + ((size_t)di * 8192 + m) * 9;
  const short* xb = xsrc + (size_t)(n << 12) * CST + lane * 8;
  float acc[8] = {0.f, 0.f, 0.f, 0.f, 0.f, 0.f, 0.f, 0.f};
#pragma unroll
  for (int k = 0; k < 9; ++k) {
    int4 e = tp[k];
    const int* ep = (const int*)&e;
#pragma unroll
    for (int c = 0; c < 4; ++c) {
      int dw = ep[c];
      float wt = __builtin_bit_cast(float, (unsigned)dw & 0xFFFF0000u);
      int row = dw & 0xFFFF;
      const short8 vv = *(const short8*)(xb + (size_t)row * CST);
#pragma unroll
      for (int j = 0; j < 8; ++j) acc[j] += wt * bf2f(vv[j]);
    }
  }
  short8 o8;
#pragma unroll
  for (int j = 0; j < 8; ++j) o8[j] = f2bf(acc[j]);
  *(short8*)(cat + (size_t)m * CST + 512 * (di + 1) + lane * 8) = o8;
}

// ---- 1x1 fuse conv, R21: LDS-traffic cut. The R18 form is LDS-read-pipe
// bound (8 waves x 12 b128/tile x 12cyc = ~46us). New: 256 thr = 4 waves
// (2Mx2N, per-wave 64x64 -> 0.5 b128/MFMA), A staged in LDS (gl16, T2
// swizzle, dbuf 32KB, prefetch dist 2), B DIRECT global->reg (no LDS at
// all for B; fragment = 16 rows x 64B lines, L1-reuse across waves).
// vmcnt choreography: per iter issue [B(t+1) x8, A(t+2) x4]; top-of-iter
// vmcnt(4) leaves A(t+1) in flight. Epilogue: Y bf16 + fused stats.
__global__ __launch_bounds__(256, 2) void k_gemm(const short* __restrict__ A,
                                                 const short* __restrict__ B,
                                                 short* __restrict__ Y,
                                                 float* __restrict__ stats) {
  __shared__ short As[2 * 128 * 64];   // 32 KB A double-buffer
  __shared__ float sred[128][2];       // 1 KB per-col {sum, sumsq}
  int tid = threadIdx.x;
  int wave = tid >> 6, lane = tid & 63;
  int l15 = lane & 15, quad = lane >> 4;
  int bid = blockIdx.x;              // 0..255
  int xcd = bid & 7, g = bid >> 3;   // per-XCD: 8 mt x 4 nt (A reused in L2)
  int mt = xcd * 8 + (g & 7);
  int nt = g >> 3;                   // 0..3
  int m0 = mt * 128, n0 = nt * 128;
  int wm = (wave >> 1) * 64;         // {0,64}
  int wn = (wave & 1) * 64;          // {0,64}
  f32x4 acc[4][4];
  f32x4 zz = {0.f, 0.f, 0.f, 0.f};
#pragma unroll
  for (int i = 0; i < 4; ++i)
#pragma unroll
    for (int j = 0; j < 4; ++j) acc[i][j] = zz;
  // A staging: chunk q = it*256 + tid; row = q>>3 (0..127), c8 = q&7;
  // source col-chunk pre-swizzled (c8 ^ row&7), LDS dest linear.
  const short* asrc[4];
  short* adst[4];
#pragma unroll
  for (int it = 0; it < 4; ++it) {
    int q = it * 256 + tid;
    int row = q >> 3, c8 = q & 7;
    asrc[it] = A + (size_t)(m0 + row) * CST + (c8 ^ (row & 7)) * 8;
    adst[it] = As + q * 8;
  }
  // B direct row bases (per-lane): row = n0 + wn + j*16 + l15, + quad chunk
  const short* bb[4];
#pragma unroll
  for (int j = 0; j < 4; ++j)
    bb[j] = B + (size_t)(n0 + wn + j * 16 + l15) * CST + quad * 8;
  short8 bA[4][2], bB[4][2];
  // prologue: A(0)->buf0, B(0)->bA, A(1)->buf1  (queue: A0[4], B0[8], A1[4])
#pragma unroll
  for (int it = 0; it < 4; ++it) gl16(asrc[it], adst[it]);
#pragma unroll
  for (int j = 0; j < 4; ++j)
#pragma unroll
    for (int kk = 0; kk < 2; ++kk)
      bA[j][kk] = *(const short8*)(bb[j] + kk * 32);
#pragma unroll
  for (int it = 0; it < 4; ++it) gl16(asrc[it] + 64, adst[it] + 8192);

#define GITER(T, BCUR, BNXT)                                                   \
  {                                                                            \
    if ((T) == 47) { asm volatile("s_waitcnt vmcnt(0)" ::: "memory"); }        \
    else           { asm volatile("s_waitcnt vmcnt(4)" ::: "memory"); }        \
    __builtin_amdgcn_s_barrier();          /* A(T) resident in LDS */          \
    __builtin_amdgcn_sched_barrier(0);                                         \
    if ((T) + 1 < 48) {                    /* issue B(T+1) -> regs */          \
      _Pragma("unroll") for (int j = 0; j < 4; ++j)                            \
        _Pragma("unroll") for (int kk = 0; kk < 2; ++kk)                       \
          BNXT[j][kk] = *(const short8*)(bb[j] + ((T) + 1) * 64 + kk * 32);    \
    }                                                                          \
    const short* Ab = As + ((T) & 1) * 8192;                                   \
    short8 a[4][2];                                                            \
    _Pragma("unroll") for (int i = 0; i < 4; ++i) {                            \
      int row = wm + i * 16 + l15;                                             \
      _Pragma("unroll") for (int kk = 0; kk < 2; ++kk)                         \
        a[i][kk] = *(const short8*)(Ab + row * 64 +                            \
                                    ((quad + kk * 4) ^ (row & 7)) * 8);        \
    }                                                                          \
    asm volatile("s_waitcnt lgkmcnt(0)" ::: "memory");                         \
    __builtin_amdgcn_sched_barrier(0);                                         \
    __builtin_amdgcn_s_barrier();          /* buf[T&1] free for rewrite */     \
    __builtin_amdgcn_sched_barrier(0);                                         \
    if ((T) + 2 < 48) {                    /* stage A(T+2) -> buf[T&1] */      \
      _Pragma("unroll") for (int it = 0; it < 4; ++it)                         \
        gl16(asrc[it] + ((T) + 2) * 64, adst[it] + ((T) & 1) * 8192);          \
    }                                                                          \
    __builtin_amdgcn_s_setprio(1);                                             \
    _Pragma("unroll") for (int kk = 0; kk < 2; ++kk)                           \
      _Pragma("unroll") for (int i = 0; i < 4; ++i)                            \
        _Pragma("unroll") for (int j = 0; j < 4; ++j)                          \
          acc[i][j] = __builtin_amdgcn_mfma_f32_16x16x32_bf16(                 \
              a[i][kk], BCUR[j][kk], acc[i][j], 0, 0, 0);                      \
    __builtin_amdgcn_s_setprio(0);                                             \
  }

#pragma unroll 1
  for (int tt = 0; tt < 48; tt += 2) {
    GITER(tt, bA, bB);
    GITER(tt + 1, bB, bA);
  }
#undef GITER
  // epilogue: Y write (bf16) + in-block per-channel sum/sumsq reduction
  __syncthreads();
  if (tid < 256) ((float*)sred)[tid] = 0.f;
  __syncthreads();
#pragma unroll
  for (int i = 0; i < 4; ++i) {
    int row = m0 + wm + i * 16 + quad * 4;
#pragma unroll
    for (int j = 0; j < 4; ++j) {
      int col = n0 + wn + j * 16 + l15;
#pragma unroll
      for (int r = 0; r < 4; ++r)
        Y[(size_t)(row + r) * 512 + col] = f2bf(acc[i][j][r]);
    }
  }
#pragma unroll
  for (int j = 0; j < 4; ++j) {
    float s = 0.f, q = 0.f;
#pragma unroll
    for (int i = 0; i < 4; ++i)
#pragma unroll
      for (int r = 0; r < 4; ++r) {
        float v = acc[i][j][r];
        s += v; q += v * v;
      }
    int lc = wn + j * 16 + l15;
    atomicAdd(&sred[lc][0], s);
    atomicAdd(&sred[lc][1], q);
  }
  __syncthreads();
  if (tid < 128) {
    atomicAdd(&stats[n0 + tid], sred[tid][0]);
    atomicAdd(&stats[512 + n0 + tid], sred[tid][1]);
  }
}

// ---- normalize Y + NHWC->NCHW transpose -> d_out. short8 loads
// (8 ch/thread), float4 stores along w, scale applied at store.
__global__ __launch_bounds__(256) void k_norm(const short* __restrict__ Y,
                                              const float* __restrict__ stats,
                                              const float* __restrict__ gamma,
                                              const float* __restrict__ beta,
                                              float* __restrict__ out) {
  __shared__ float tile[64][65];
  int b = blockIdx.x;
  int cblk = b & 7, h = (b >> 3) & 63, n = b >> 9;
  int c0 = cblk * 64;
  int t = threadIdx.x;
  size_t mbase = ((size_t)n * 64 + h) * 64;
  int c8 = t & 7, wq = t >> 3;
#pragma unroll
  for (int it = 0; it < 2; ++it) {
    int w = wq + it * 32;
    size_t ro = (mbase + w) * 512 + c0 + c8 * 8;
    short8 a = *(const short8*)(Y + ro);
#pragma unroll
    for (int j = 0; j < 8; ++j) tile[w][c8 * 8 + j] = bf2f(a[j]);
  }
  __syncthreads();
  int w4 = (t & 15) * 4, cg = t >> 4;
  float* op = out + (((size_t)n * 512 + c0) * 64 + h) * 64;
#pragma unroll
  for (int i = 0; i < 4; ++i) {
    int c2 = cg * 4 + i;
    int cc = c0 + c2;
    float mean = stats[cc] * (1.f / 8192.f);
    float var = stats[512 + cc] * (1.f / 8192.f) - mean * mean;
    float Ai = gamma[cc] * rsqrtf(var + 1e-5f);
    float Bi = beta[cc] - mean * Ai;
    float4 o;
    o.x = tile[w4 + 0][c2] * Ai + Bi;
    o.y = tile[w4 + 1][c2] * Ai + Bi;
    o.z = tile[w4 + 2][c2] * Ai + Bi;
    o.w = tile[w4 + 3][c2] * Ai + Bi;
    *(float4*)(op + (size_t)c2 * 4096 + w4) = o;
  }
}

extern "C" void kernel_launch(void* const* d_in, const int* in_sizes, int n_in,
                              void* d_out, int out_size, void* d_ws, size_t ws_size,
                              hipStream_t stream) {
  const float* x  = (const float*)d_in[0];
  const float* w1 = (const float*)d_in[1];
  const float* w2 = (const float*)d_in[2];
  const float* w3 = (const float*)d_in[3];
  const float* w4 = (const float*)d_in[4];
  const float* w5 = (const float*)d_in[5];
  const float* sw = (const float*)d_in[6];
  const float* gamma = (const float*)d_in[7];
  const float* beta  = (const float*)d_in[8];
  float* out = (float*)d_out;

  char* ws = (char*)d_ws;
  // workspace layout (bytes):
  // cat   @ 0        : 8192*3072*2    = 50331648   (bf16, block0 = x NHWC)
  // wbf   @ 50331648 : 512*3072*2     = 3145728
  // wdr   @ 53477376 : 5*9*32*512*2   = 1474560
  // yb    @ 54951936 : 8192*512*2     = 8388608    (single bf16 full-K Y)
  // stats @ 71729152 : 1024*4         = 4096
  // ctab  @ 71733248 : 40960*36*4     = 5898240    (corner table)
  short* cat   = (short*)ws;
  short* wbf   = (short*)(ws + 50331648);
  short* wdr   = (short*)(ws + 53477376);
  short* yb    = (short*)(ws + 54951936);
  float* stats = (float*)(ws + 71729152);
  int*   ctab  = (int*)(ws + 71733248);

  k_init<<<4676, 256, 0, stream>>>(x, sw, w1, w2, w3, w4, w5, cat, wbf, wdr, stats);
  k_conv<<<640, 128, 0, stream>>>(cat, wdr, ctab);
  k_samp<<<10240, 256, 0, stream>>>(cat, cat, ctab);
  k_gemm<<<256, 256, 0, stream>>>(cat, wbf, yb, stats);
  k_norm<<<1024, 256, 0, stream>>>(yb, stats, gamma, beta, out);
}

// Round 8
// 236.511 us; speedup vs baseline: 1.0108x; 1.0108x over previous
//
#include <hip/hip_runtime.h>

typedef short short8 __attribute__((ext_vector_type(8)));
typedef float f32x4 __attribute__((ext_vector_type(4)));

#define CST 3072  // cat row stride (6*512 channels)

__device__ __forceinline__ float bf2f(short s) {
  unsigned u = ((unsigned)(unsigned short)s) << 16;
  return __builtin_bit_cast(float, u);
}
__device__ __forceinline__ short f2bf(float f) {
  unsigned u = __builtin_bit_cast(unsigned, f);
  u = (u + 0x7FFFu + ((u >> 16) & 1u)) >> 16;
  return (short)u;
}
__device__ __forceinline__ void gl16(const short* g, short* l) {
  __builtin_amdgcn_global_load_lds(
      (const __attribute__((address_space(1))) unsigned*)g,
      (__attribute__((address_space(3))) unsigned*)l, 16, 0, 0);
}

// ---- merged init: blocks <1024 do NCHW->NHWC bf16 transpose of x
// (vectorized short8 stores); blocks 1024..1791 scale_w->bf16 (8 elem/thr);
// 1792..4671 wdr reorder; 4672..4675 stats zero.
__global__ __launch_bounds__(256) void k_init(const float* __restrict__ x,
                                              const float* __restrict__ sw,
                                              const float* __restrict__ w1, const float* __restrict__ w2,
                                              const float* __restrict__ w3, const float* __restrict__ w4,
                                              const float* __restrict__ w5,
                                              short* __restrict__ cat,
                                              short* __restrict__ wbf, short* __restrict__ wdr,
                                              float* __restrict__ stats) {
  __shared__ float tile[64][65];
  int b = blockIdx.x;
  int t = threadIdx.x;
  if (b < 1024) {
    int cblk = b & 7, h = (b >> 3) & 63, n = b >> 9;
    int c0 = cblk * 64;
    int lw = t & 63, grp = t >> 6;
    const float* xp = x + (((size_t)n * 512 + c0) * 64 + h) * 64;
#pragma unroll
    for (int i = 0; i < 16; ++i) {
      int cl = grp * 16 + i;
      tile[cl][lw] = xp[(size_t)cl * 4096 + lw];
    }
    __syncthreads();
    // store: thread -> (channel octet c8 = t&7, w = t>>3 (+32)); short8 writes
    int c8 = t & 7, wq = t >> 3;
    size_t mbase = ((size_t)n * 64 + h) * 64;
#pragma unroll
    for (int it = 0; it < 2; ++it) {
      int w = wq + it * 32;
      short8 o;
#pragma unroll
      for (int j = 0; j < 8; ++j) o[j] = f2bf(tile[c8 * 8 + j][w]);
      *(short8*)(cat + (mbase + w) * CST + c0 + c8 * 8) = o;
    }
  } else if (b < 1792) {
    // scale_w -> bf16, 8 elements per thread
    int i8 = (b - 1024) * 256 + t;
    const float4* sp = (const float4*)(sw + (size_t)i8 * 8);
    float4 f0 = sp[0], f1 = sp[1];
    short8 o;
    o[0] = f2bf(f0.x); o[1] = f2bf(f0.y); o[2] = f2bf(f0.z); o[3] = f2bf(f0.w);
    o[4] = f2bf(f1.x); o[5] = f2bf(f1.y); o[6] = f2bf(f1.z); o[7] = f2bf(f1.w);
    *(short8*)(wbf + (size_t)i8 * 8) = o;
  } else if (b < 4672) {
    int j = (b - 1792) * 256 + t;
    int c = j & 511;
    int t2 = j >> 9;
    int oc = t2 & 31;
    int t3 = t2 >> 5;
    int tap = t3 % 9;
    int di = t3 / 9;
    float v = 0.f;
    if (oc < 27) {
      const float* wp = (di == 0) ? w1 : (di == 1) ? w2 : (di == 2) ? w3 : (di == 3) ? w4 : w5;
      v = wp[((oc * 512 + c) * 3 + tap / 3) * 3 + tap % 3];
    }
    wdr[j] = f2bf(v);
  } else {
    int idx = (b - 4672) * 256 + t;
    stats[idx] = 0.f;
  }
}

// ---- offset conv + softmax + corner-table build. [R4 form — measured best]
// Block = 128 thr (2 waves) = one image row (n,h): 64 positions.
// Wave covers 32 positions (2 m-tiles sharing B-frags): 2 b128/pos/tap.
// K split in halves (kh): LDS = A 32 KB + B 16 KB = 48 KB -> 3 blocks/CU
// (fo buffer aliases As: written only after all MFMA reads, extra barrier).
// Swizzle: LDS slot (row,ch) holds source chunk ch^(row&7).
// C/D layout: row (m=position) = quad*4+reg, col (n=oc) = l15.
__global__ __launch_bounds__(128) void k_conv(const short* __restrict__ xsrc,
                                              const short* __restrict__ wdr_all,
                                              int* __restrict__ ctab) {
  __shared__ short As[64 * 256];   // 32 KB: 64 cols x 256 ch (kh half)
  __shared__ short Bs[32 * 256];   // 16 KB: 32 oc x 256 ch
  float (*fo)[32][33] = (float (*)[32][33])(void*)As;  // aliased: used post-MFMA
  int tid = threadIdx.x;
  int wave = tid >> 6, lane = tid & 63;
  int l15 = lane & 15, quad = lane >> 4;
  int b = blockIdx.x;
  int di = b >> 7;
  int loc = b & 127;
  const int DIL[5] = {1, 6, 12, 24, 36};
  int d = DIL[di];
  int rid = (loc & 7) * 16 + (loc >> 3);  // xcd-affine row id (0..127)
  int h = rid & 63, n = rid >> 6;         // block-uniform row
  f32x4 acc[2][2];
  f32x4 zz = {0.f, 0.f, 0.f, 0.f};
#pragma unroll
  for (int i = 0; i < 2; ++i)
#pragma unroll
    for (int j = 0; j < 2; ++j) acc[i][j] = zz;
  const short8 z8 = {0, 0, 0, 0, 0, 0, 0, 0};
  // per-lane staging source offsets (slot q = i*128 + tid)
  int aoff[16];
  int boff[8];
#pragma unroll
  for (int i = 0; i < 16; ++i) {
    int q = i * 128 + tid;
    int w = q >> 5, ch = q & 31;
    aoff[i] = w * CST + (ch ^ (w & 7)) * 8;
  }
#pragma unroll
  for (int i = 0; i < 8; ++i) {
    int q = i * 128 + tid;
    int oc = q >> 5, ch = q & 31;
    boff[i] = oc * 512 + (ch ^ (oc & 7)) * 8;
  }
  const short* wbase = wdr_all + (size_t)di * 9 * 32 * 512;
  int rowb = (n << 12);
#pragma unroll 1
  for (int kh = 0; kh < 2; ++kh) {
    int lastty = -1;
#pragma unroll
    for (int tap = 0; tap < 9; ++tap) {
      int ty = tap / 3, tx = tap % 3;
      int hh = h + (ty - 1) * d;
      if ((unsigned)hh >= 64u) continue;   // block-uniform skip
      __syncthreads();                     // prior LDS reads complete
      if (ty != lastty) {                  // stage full row hh (A), kh half
        const short* abase = xsrc + (size_t)(rowb + (hh << 6)) * CST + kh * 256;
#pragma unroll
        for (int i = 0; i < 16; ++i)
          gl16(abase + aoff[i], As + (i * 128 + wave * 64) * 8);
        lastty = ty;
      }
      {                                    // stage B tap, kh half
        const short* bbase = wbase + tap * 32 * 512 + kh * 256;
#pragma unroll
        for (int i = 0; i < 8; ++i)
          gl16(bbase + boff[i], Bs + (i * 128 + wave * 64) * 8);
      }
      __syncthreads();                     // gl16 drained
      int s0 = wave * 32 + (tx - 1) * d;   // col of (mt,l15): s0 + mt*16 + l15
#pragma unroll
      for (int ks = 0; ks < 8; ++ks) {
        int c = ks * 4 + quad;
        short8 a[2], bb[2];
#pragma unroll
        for (int mt = 0; mt < 2; ++mt) {
          int wp = s0 + mt * 16 + l15;
          bool ok = (unsigned)wp < 64u;
          int wc = ok ? wp : 0;
          short8 av = *(const short8*)(As + wc * 256 + (c ^ (wc & 7)) * 8);
          a[mt] = ok ? av : z8;
        }
#pragma unroll
        for (int ot = 0; ot < 2; ++ot) {
          int oc = ot * 16 + l15;
          bb[ot] = *(const short8*)(Bs + oc * 256 + (c ^ (oc & 7)) * 8);
        }
#pragma unroll
        for (int mt = 0; mt < 2; ++mt)
#pragma unroll
          for (int ot = 0; ot < 2; ++ot)
            acc[mt][ot] = __builtin_amdgcn_mfma_f32_16x16x32_bf16(a[mt], bb[ot], acc[mt][ot], 0, 0, 0);
      }
    }
  }
  __syncthreads();   // all waves done reading As before fo (aliased) is written
  // write fo: C row (quad*4+r) = position, C col (l15) = oc
#pragma unroll
  for (int mt = 0; mt < 2; ++mt)
#pragma unroll
    for (int ot = 0; ot < 2; ++ot)
#pragma unroll
      for (int r = 0; r < 4; ++r)
        fo[wave][mt * 16 + quad * 4 + r][ot * 16 + l15] = acc[mt][ot][r];
  __syncthreads();
  if (tid < 64) {   // softmax: one position per thread (wave0)
    int p = tid;
    float* fp = fo[p >> 5][p & 31];
    float mx = fp[0];
#pragma unroll
    for (int k = 1; k < 9; ++k) mx = fmaxf(mx, fp[k]);
    float s = 0.f, e[9];
#pragma unroll
    for (int k = 0; k < 9; ++k) { e[k] = __expf(fp[k] - mx); s += e[k]; }
    float inv = 1.f / s;
#pragma unroll
    for (int k = 0; k < 9; ++k) fp[k] = e[k] * inv;
  }
  __syncthreads();
  // corner table: 64 pos x 9 taps = 576 tasks over 128 threads, 5 rounds
#pragma unroll
  for (int rr = 0; rr < 5; ++rr) {
    int task = rr * 128 + tid;
    if (task < 576) {
      int p = task / 9;
      int k = task - p * 9;
      const float* fp = fo[p >> 5][p & 31];
      float f = fp[k];
      float dy = fp[9 + 2 * k];
      float dx = fp[10 + 2 * k];
      float ys = (float)(h + (k / 3 - 1) * d) + dy;
      float xs = (float)(p + (k % 3 - 1) * d) + dx;
      float y0f = floorf(ys), x0f = floorf(xs);
      float wy1 = ys - y0f, wx1 = xs - x0f;
      float wy0 = 1.f - wy1, wx0 = 1.f - wx1;
      int y0 = (int)y0f, x0 = (int)x0f;
      int4 ent;
      int* ep = (int*)&ent;
#pragma unroll
      for (int cy = 0; cy < 2; ++cy)
#pragma unroll
        for (int cx = 0; cx < 2; ++cx) {
          int yy = y0 + cy, xx = x0 + cx;
          bool v = ((unsigned)yy < 64u) && ((unsigned)xx < 64u);
          float wt = f * (cy ? wy1 : wy0) * (cx ? wx1 : wx0);
          int row = v ? (yy * 64 + xx) : 0;
          unsigned wb = v ? (unsigned)(unsigned short)f2bf(wt) : 0u;
          ep[cy * 2 + cx] = row | (int)(wb << 16);
        }
      int mm = rowb + (h << 6) + p;
      ((int4*)ctab)[((size_t)di * 8192 + mm) * 9 + k] = ent;
    }
  }
}

// ---- deform bilinear sample from precomputed corner table (R10/R12 form:
// one position per wave — measured local optimum; channel-split (R15) was
// 20% WORSE: two discontiguous 512B segments/instr + 2x ctab reads).
__global__ __launch_bounds__(256, 4) void k_samp(const short* __restrict__ xsrc,
                                                 short* __restrict__ cat,
                                                 const int* __restrict__ ctab) {
  int tid = threadIdx.x;
  int wv = __builtin_amdgcn_readfirstlane(tid >> 6);
  int lane = tid & 63;
  int b = blockIdx.x;
  int di = b >> 11;
  int loc = b & 2047;
  int m = (loc & 7) * 1024 + (loc >> 3) * 4 + wv;  // xcd*1024 + slab*4 + wave
  int n = m >> 12;
  const int4* tp = (const int4*)ctab + ((size_t)di * 8192 + m) * 9;
  const short* xb = xsrc + (size_t)(n << 12) * CST + lane * 8;
  float acc[8] = {0.f, 0.f, 0.f, 0.f, 0.f, 0.f, 0.f, 0.f};
#pragma unroll
  for (int k = 0; k < 9; ++k) {
    int4 e = tp[k];
    const int* ep = (const int*)&e;
#pragma unroll
    for (int c = 0; c < 4; ++c) {
      int dw = ep[c];
      float wt = __builtin_bit_cast(float, (unsigned)dw & 0xFFFF0000u);
      int row = dw & 0xFFFF;
      const short8 vv = *(const short8*)(xb + (size_t)row * CST);
#pragma unroll
      for (int j = 0; j < 8; ++j) acc[j] += wt * bf2f(vv[j]);
    }
  }
  short8 o8;
#pragma unroll
  for (int j = 0; j < 8; ++j) o8[j] = f2bf(acc[j]);
  *(short8*)(cat + (size_t)m * CST + 512 * (di + 1) + lane * 8) = o8;
}

// ---- 1x1 fuse conv, R22 = R18 occupancy + R21 traffic cut.
// 512 thr = 8 waves (2M x 4N, per-wave 64x32), BM=BN=128, grid 256 = 1/CU
// -> 8 waves/CU = 2/SIMD (R18-proven latency cover; R21's 256-thr form
// collapsed to 1 wave/SIMD -> 75us latency-bound).
// A staged in LDS (gl16, T2 swizzle, 32KB dbuf, dist-2 prefetch): 8 b128
// reads/wave/tile (vs R18's 12 — B no longer in LDS).
// B DIRECT global->reg, 1-iter prefetch (4 loads/wave/tile, L1/L2-served).
// vmcnt: queue/wave = [A(t)4, B(t)4, A(t+1)4]; top-of-iter vmcnt(4)
// drains A(t)+B(t), leaves A(t+1). Epilogue: Y bf16 + fused stats.
__global__ __launch_bounds__(512, 2) void k_gemm(const short* __restrict__ A,
                                                 const short* __restrict__ B,
                                                 short* __restrict__ Y,
                                                 float* __restrict__ stats) {
  __shared__ short As[2 * 128 * 64];   // 32 KB A double-buffer
  __shared__ float sred[128][2];       // 1 KB per-col {sum, sumsq}
  int tid = threadIdx.x;
  int wave = tid >> 6, lane = tid & 63;
  int l15 = lane & 15, quad = lane >> 4;
  int bid = blockIdx.x;              // 0..255
  int xcd = bid & 7, g = bid >> 3;   // per-XCD: 8 mt x 4 nt (A reused in L2)
  int mt = xcd * 8 + (g & 7);
  int nt = g >> 3;                   // 0..3
  int m0 = mt * 128, n0 = nt * 128;
  int wm = (wave >> 2) * 64;         // {0,64}
  int wn = (wave & 3) * 32;          // {0,32,64,96}
  f32x4 acc[4][2];
  f32x4 zz = {0.f, 0.f, 0.f, 0.f};
#pragma unroll
  for (int i = 0; i < 4; ++i)
#pragma unroll
    for (int j = 0; j < 2; ++j) acc[i][j] = zz;
  // A staging: chunk q = it*512 + tid; row = q>>3 (0..127), c8 = q&7;
  // source col-chunk pre-swizzled (c8 ^ row&7), LDS dest linear.
  const short* asrc[2];
  short* adst[2];
#pragma unroll
  for (int it = 0; it < 2; ++it) {
    int q = it * 512 + tid;
    int row = q >> 3, c8 = q & 7;
    asrc[it] = A + (size_t)(m0 + row) * CST + (c8 ^ (row & 7)) * 8;
    adst[it] = As + q * 8;
  }
  // B direct row bases (per-lane): row = n0 + wn + j*16 + l15, + quad chunk
  const short* bb[2];
#pragma unroll
  for (int j = 0; j < 2; ++j)
    bb[j] = B + (size_t)(n0 + wn + j * 16 + l15) * CST + quad * 8;
  short8 bA[2][2], bB[2][2];
  // prologue: A(0)->buf0, B(0)->bA, A(1)->buf1 (queue: A0[2..], B0[4], A1[..])
#pragma unroll
  for (int it = 0; it < 2; ++it) gl16(asrc[it], adst[it]);
#pragma unroll
  for (int j = 0; j < 2; ++j)
#pragma unroll
    for (int kk = 0; kk < 2; ++kk)
      bA[j][kk] = *(const short8*)(bb[j] + kk * 32);
#pragma unroll
  for (int it = 0; it < 2; ++it) gl16(asrc[it] + 64, adst[it] + 8192);

#define GITER(T, BCUR, BNXT)                                                   \
  {                                                                            \
    if ((T) == 47) { asm volatile("s_waitcnt vmcnt(0)" ::: "memory"); }        \
    else           { asm volatile("s_waitcnt vmcnt(2)" ::: "memory"); }        \
    __builtin_amdgcn_s_barrier();          /* A(T) resident in LDS */          \
    __builtin_amdgcn_sched_barrier(0);                                         \
    if ((T) + 1 < 48) {                    /* issue B(T+1) -> regs */          \
      _Pragma("unroll") for (int j = 0; j < 2; ++j)                            \
        _Pragma("unroll") for (int kk = 0; kk < 2; ++kk)                       \
          BNXT[j][kk] = *(const short8*)(bb[j] + ((T) + 1) * 64 + kk * 32);    \
    }                                                                          \
    const short* Ab = As + ((T) & 1) * 8192;                                   \
    short8 a[4][2];                                                            \
    _Pragma("unroll") for (int i = 0; i < 4; ++i) {                            \
      int row = wm + i * 16 + l15;                                             \
      _Pragma("unroll") for (int kk = 0; kk < 2; ++kk)                         \
        a[i][kk] = *(const short8*)(Ab + row * 64 +                            \
                                    ((quad + kk * 4) ^ (row & 7)) * 8);        \
    }                                                                          \
    asm volatile("s_waitcnt lgkmcnt(0)" ::: "memory");                         \
    __builtin_amdgcn_sched_barrier(0);                                         \
    __builtin_amdgcn_s_barrier();          /* buf[T&1] free for rewrite */     \
    __builtin_amdgcn_sched_barrier(0);                                         \
    if ((T) + 2 < 48) {                    /* stage A(T+2) -> buf[T&1] */      \
      _Pragma("unroll") for (int it = 0; it < 2; ++it)                         \
        gl16(asrc[it] + ((T) + 2) * 64, adst[it] + ((T) & 1) * 8192);          \
    }                                                                          \
    __builtin_amdgcn_s_setprio(1);                                             \
    _Pragma("unroll") for (int kk = 0; kk < 2; ++kk)                           \
      _Pragma("unroll") for (int i = 0; i < 4; ++i)                            \
        _Pragma("unroll") for (int j = 0; j < 2; ++j)                          \
          acc[i][j] = __builtin_amdgcn_mfma_f32_16x16x32_bf16(                 \
              a[i][kk], BCUR[j][kk], acc[i][j], 0, 0, 0);                      \
    __builtin_amdgcn_s_setprio(0);                                             \
  }

#pragma unroll 1
  for (int tt = 0; tt < 48; tt += 2) {
    GITER(tt, bA, bB);
    GITER(tt + 1, bB, bA);
  }
#undef GITER
  // epilogue: Y write (bf16) + in-block per-channel sum/sumsq reduction
  __syncthreads();
  if (tid < 256) ((float*)sred)[tid] = 0.f;
  __syncthreads();
#pragma unroll
  for (int i = 0; i < 4; ++i) {
    int row = m0 + wm + i * 16 + quad * 4;
#pragma unroll
    for (int j = 0; j < 2; ++j) {
      int col = n0 + wn + j * 16 + l15;
#pragma unroll
      for (int r = 0; r < 4; ++r)
        Y[(size_t)(row + r) * 512 + col] = f2bf(acc[i][j][r]);
    }
  }
#pragma unroll
  for (int j = 0; j < 2; ++j) {
    float s = 0.f, q = 0.f;
#pragma unroll
    for (int i = 0; i < 4; ++i)
#pragma unroll
      for (int r = 0; r < 4; ++r) {
        float v = acc[i][j][r];
        s += v; q += v * v;
      }
    int lc = wn + j * 16 + l15;
    atomicAdd(&sred[lc][0], s);
    atomicAdd(&sred[lc][1], q);
  }
  __syncthreads();
  if (tid < 128) {
    atomicAdd(&stats[n0 + tid], sred[tid][0]);
    atomicAdd(&stats[512 + n0 + tid], sred[tid][1]);
  }
}

// ---- normalize Y + NHWC->NCHW transpose -> d_out. short8 loads
// (8 ch/thread), float4 stores along w, scale applied at store.
__global__ __launch_bounds__(256) void k_norm(const short* __restrict__ Y,
                                              const float* __restrict__ stats,
                                              const float* __restrict__ gamma,
                                              const float* __restrict__ beta,
                                              float* __restrict__ out) {
  __shared__ float tile[64][65];
  int b = blockIdx.x;
  int cblk = b & 7, h = (b >> 3) & 63, n = b >> 9;
  int c0 = cblk * 64;
  int t = threadIdx.x;
  size_t mbase = ((size_t)n * 64 + h) * 64;
  int c8 = t & 7, wq = t >> 3;
#pragma unroll
  for (int it = 0; it < 2; ++it) {
    int w = wq + it * 32;
    size_t ro = (mbase + w) * 512 + c0 + c8 * 8;
    short8 a = *(const short8*)(Y + ro);
#pragma unroll
    for (int j = 0; j < 8; ++j) tile[w][c8 * 8 + j] = bf2f(a[j]);
  }
  __syncthreads();
  int w4 = (t & 15) * 4, cg = t >> 4;
  float* op = out + (((size_t)n * 512 + c0) * 64 + h) * 64;
#pragma unroll
  for (int i = 0; i < 4; ++i) {
    int c2 = cg * 4 + i;
    int cc = c0 + c2;
    float mean = stats[cc] * (1.f / 8192.f);
    float var = stats[512 + cc] * (1.f / 8192.f) - mean * mean;
    float Ai = gamma[cc] * rsqrtf(var + 1e-5f);
    float Bi = beta[cc] - mean * Ai;
    float4 o;
    o.x = tile[w4 + 0][c2] * Ai + Bi;
    o.y = tile[w4 + 1][c2] * Ai + Bi;
    o.z = tile[w4 + 2][c2] * Ai + Bi;
    o.w = tile[w4 + 3][c2] * Ai + Bi;
    *(float4*)(op + (size_t)c2 * 4096 + w4) = o;
  }
}

extern "C" void kernel_launch(void* const* d_in, const int* in_sizes, int n_in,
                              void* d_out, int out_size, void* d_ws, size_t ws_size,
                              hipStream_t stream) {
  const float* x  = (const float*)d_in[0];
  const float* w1 = (const float*)d_in[1];
  const float* w2 = (const float*)d_in[2];
  const float* w3 = (const float*)d_in[3];
  const float* w4 = (const float*)d_in[4];
  const float* w5 = (const float*)d_in[5];
  const float* sw = (const float*)d_in[6];
  const float* gamma = (const float*)d_in[7];
  const float* beta  = (const float*)d_in[8];
  float* out = (float*)d_out;

  char* ws = (char*)d_ws;
  // workspace layout (bytes):
  // cat   @ 0        : 8192*3072*2    = 50331648   (bf16, block0 = x NHWC)
  // wbf   @ 50331648 : 512*3072*2     = 3145728
  // wdr   @ 53477376 : 5*9*32*512*2   = 1474560
  // yb    @ 54951936 : 8192*512*2     = 8388608    (single bf16 full-K Y)
  // stats @ 71729152 : 1024*4         = 4096
  // ctab  @ 71733248 : 40960*36*4     = 5898240    (corner table)
  short* cat   = (short*)ws;
  short* wbf   = (short*)(ws + 50331648);
  short* wdr   = (short*)(ws + 53477376);
  short* yb    = (short*)(ws + 54951936);
  float* stats = (float*)(ws + 71729152);
  int*   ctab  = (int*)(ws + 71733248);

  k_init<<<4676, 256, 0, stream>>>(x, sw, w1, w2, w3, w4, w5, cat, wbf, wdr, stats);
  k_conv<<<640, 128, 0, stream>>>(cat, wdr, ctab);
  k_samp<<<10240, 256, 0, stream>>>(cat, cat, ctab);
  k_gemm<<<256, 512, 0, stream>>>(cat, wbf, yb, stats);
  k_norm<<<1024, 256, 0, stream>>>(yb, stats, gamma, beta, out);
}

// Round 9
// 213.996 us; speedup vs baseline: 1.1171x; 1.1052x over previous
//
#include <hip/hip_runtime.h>

typedef short short8 __attribute__((ext_vector_type(8)));
typedef float f32x4 __attribute__((ext_vector_type(4)));

#define CST 3072  // cat row stride (6*512 channels)

__device__ __forceinline__ float bf2f(short s) {
  unsigned u = ((unsigned)(unsigned short)s) << 16;
  return __builtin_bit_cast(float, u);
}
__device__ __forceinline__ short f2bf(float f) {
  unsigned u = __builtin_bit_cast(unsigned, f);
  u = (u + 0x7FFFu + ((u >> 16) & 1u)) >> 16;
  return (short)u;
}
__device__ __forceinline__ void gl16(const short* g, short* l) {
  __builtin_amdgcn_global_load_lds(
      (const __attribute__((address_space(1))) unsigned*)g,
      (__attribute__((address_space(3))) unsigned*)l, 16, 0, 0);
}

// ---- merged init: blocks <1024 do NCHW->NHWC bf16 transpose of x
// (vectorized short8 stores); blocks 1024..1791 scale_w->bf16 (8 elem/thr);
// 1792..4671 wdr reorder; 4672..4675 stats zero.
__global__ __launch_bounds__(256) void k_init(const float* __restrict__ x,
                                              const float* __restrict__ sw,
                                              const float* __restrict__ w1, const float* __restrict__ w2,
                                              const float* __restrict__ w3, const float* __restrict__ w4,
                                              const float* __restrict__ w5,
                                              short* __restrict__ cat,
                                              short* __restrict__ wbf, short* __restrict__ wdr,
                                              float* __restrict__ stats) {
  __shared__ float tile[64][65];
  int b = blockIdx.x;
  int t = threadIdx.x;
  if (b < 1024) {
    int cblk = b & 7, h = (b >> 3) & 63, n = b >> 9;
    int c0 = cblk * 64;
    int lw = t & 63, grp = t >> 6;
    const float* xp = x + (((size_t)n * 512 + c0) * 64 + h) * 64;
#pragma unroll
    for (int i = 0; i < 16; ++i) {
      int cl = grp * 16 + i;
      tile[cl][lw] = xp[(size_t)cl * 4096 + lw];
    }
    __syncthreads();
    // store: thread -> (channel octet c8 = t&7, w = t>>3 (+32)); short8 writes
    int c8 = t & 7, wq = t >> 3;
    size_t mbase = ((size_t)n * 64 + h) * 64;
#pragma unroll
    for (int it = 0; it < 2; ++it) {
      int w = wq + it * 32;
      short8 o;
#pragma unroll
      for (int j = 0; j < 8; ++j) o[j] = f2bf(tile[c8 * 8 + j][w]);
      *(short8*)(cat + (mbase + w) * CST + c0 + c8 * 8) = o;
    }
  } else if (b < 1792) {
    // scale_w -> bf16, 8 elements per thread
    int i8 = (b - 1024) * 256 + t;
    const float4* sp = (const float4*)(sw + (size_t)i8 * 8);
    float4 f0 = sp[0], f1 = sp[1];
    short8 o;
    o[0] = f2bf(f0.x); o[1] = f2bf(f0.y); o[2] = f2bf(f0.z); o[3] = f2bf(f0.w);
    o[4] = f2bf(f1.x); o[5] = f2bf(f1.y); o[6] = f2bf(f1.z); o[7] = f2bf(f1.w);
    *(short8*)(wbf + (size_t)i8 * 8) = o;
  } else if (b < 4672) {
    int j = (b - 1792) * 256 + t;
    int c = j & 511;
    int t2 = j >> 9;
    int oc = t2 & 31;
    int t3 = t2 >> 5;
    int tap = t3 % 9;
    int di = t3 / 9;
    float v = 0.f;
    if (oc < 27) {
      const float* wp = (di == 0) ? w1 : (di == 1) ? w2 : (di == 2) ? w3 : (di == 3) ? w4 : w5;
      v = wp[((oc * 512 + c) * 3 + tap / 3) * 3 + tap % 3];
    }
    wdr[j] = f2bf(v);
  } else {
    int idx = (b - 4672) * 256 + t;
    stats[idx] = 0.f;
  }
}

// ---- offset conv + softmax + corner-table build. [R4 form — measured best]
// Block = 128 thr (2 waves) = one image row (n,h): 64 positions.
// Wave covers 32 positions (2 m-tiles sharing B-frags): 2 b128/pos/tap.
// K split in halves (kh): LDS = A 32 KB + B 16 KB = 48 KB -> 3 blocks/CU
// (fo buffer aliases As: written only after all MFMA reads, extra barrier).
// Swizzle: LDS slot (row,ch) holds source chunk ch^(row&7).
// C/D layout: row (m=position) = quad*4+reg, col (n=oc) = l15.
__global__ __launch_bounds__(128) void k_conv(const short* __restrict__ xsrc,
                                              const short* __restrict__ wdr_all,
                                              int* __restrict__ ctab) {
  __shared__ short As[64 * 256];   // 32 KB: 64 cols x 256 ch (kh half)
  __shared__ short Bs[32 * 256];   // 16 KB: 32 oc x 256 ch
  float (*fo)[32][33] = (float (*)[32][33])(void*)As;  // aliased: used post-MFMA
  int tid = threadIdx.x;
  int wave = tid >> 6, lane = tid & 63;
  int l15 = lane & 15, quad = lane >> 4;
  int b = blockIdx.x;
  int di = b >> 7;
  int loc = b & 127;
  const int DIL[5] = {1, 6, 12, 24, 36};
  int d = DIL[di];
  int rid = (loc & 7) * 16 + (loc >> 3);  // xcd-affine row id (0..127)
  int h = rid & 63, n = rid >> 6;         // block-uniform row
  f32x4 acc[2][2];
  f32x4 zz = {0.f, 0.f, 0.f, 0.f};
#pragma unroll
  for (int i = 0; i < 2; ++i)
#pragma unroll
    for (int j = 0; j < 2; ++j) acc[i][j] = zz;
  const short8 z8 = {0, 0, 0, 0, 0, 0, 0, 0};
  // per-lane staging source offsets (slot q = i*128 + tid)
  int aoff[16];
  int boff[8];
#pragma unroll
  for (int i = 0; i < 16; ++i) {
    int q = i * 128 + tid;
    int w = q >> 5, ch = q & 31;
    aoff[i] = w * CST + (ch ^ (w & 7)) * 8;
  }
#pragma unroll
  for (int i = 0; i < 8; ++i) {
    int q = i * 128 + tid;
    int oc = q >> 5, ch = q & 31;
    boff[i] = oc * 512 + (ch ^ (oc & 7)) * 8;
  }
  const short* wbase = wdr_all + (size_t)di * 9 * 32 * 512;
  int rowb = (n << 12);
#pragma unroll 1
  for (int kh = 0; kh < 2; ++kh) {
    int lastty = -1;
#pragma unroll
    for (int tap = 0; tap < 9; ++tap) {
      int ty = tap / 3, tx = tap % 3;
      int hh = h + (ty - 1) * d;
      if ((unsigned)hh >= 64u) continue;   // block-uniform skip
      __syncthreads();                     // prior LDS reads complete
      if (ty != lastty) {                  // stage full row hh (A), kh half
        const short* abase = xsrc + (size_t)(rowb + (hh << 6)) * CST + kh * 256;
#pragma unroll
        for (int i = 0; i < 16; ++i)
          gl16(abase + aoff[i], As + (i * 128 + wave * 64) * 8);
        lastty = ty;
      }
      {                                    // stage B tap, kh half
        const short* bbase = wbase + tap * 32 * 512 + kh * 256;
#pragma unroll
        for (int i = 0; i < 8; ++i)
          gl16(bbase + boff[i], Bs + (i * 128 + wave * 64) * 8);
      }
      __syncthreads();                     // gl16 drained
      int s0 = wave * 32 + (tx - 1) * d;   // col of (mt,l15): s0 + mt*16 + l15
#pragma unroll
      for (int ks = 0; ks < 8; ++ks) {
        int c = ks * 4 + quad;
        short8 a[2], bb[2];
#pragma unroll
        for (int mt = 0; mt < 2; ++mt) {
          int wp = s0 + mt * 16 + l15;
          bool ok = (unsigned)wp < 64u;
          int wc = ok ? wp : 0;
          short8 av = *(const short8*)(As + wc * 256 + (c ^ (wc & 7)) * 8);
          a[mt] = ok ? av : z8;
        }
#pragma unroll
        for (int ot = 0; ot < 2; ++ot) {
          int oc = ot * 16 + l15;
          bb[ot] = *(const short8*)(Bs + oc * 256 + (c ^ (oc & 7)) * 8);
        }
#pragma unroll
        for (int mt = 0; mt < 2; ++mt)
#pragma unroll
          for (int ot = 0; ot < 2; ++ot)
            acc[mt][ot] = __builtin_amdgcn_mfma_f32_16x16x32_bf16(a[mt], bb[ot], acc[mt][ot], 0, 0, 0);
      }
    }
  }
  __syncthreads();   // all waves done reading As before fo (aliased) is written
  // write fo: C row (quad*4+r) = position, C col (l15) = oc
#pragma unroll
  for (int mt = 0; mt < 2; ++mt)
#pragma unroll
    for (int ot = 0; ot < 2; ++ot)
#pragma unroll
      for (int r = 0; r < 4; ++r)
        fo[wave][mt * 16 + quad * 4 + r][ot * 16 + l15] = acc[mt][ot][r];
  __syncthreads();
  if (tid < 64) {   // softmax: one position per thread (wave0)
    int p = tid;
    float* fp = fo[p >> 5][p & 31];
    float mx = fp[0];
#pragma unroll
    for (int k = 1; k < 9; ++k) mx = fmaxf(mx, fp[k]);
    float s = 0.f, e[9];
#pragma unroll
    for (int k = 0; k < 9; ++k) { e[k] = __expf(fp[k] - mx); s += e[k]; }
    float inv = 1.f / s;
#pragma unroll
    for (int k = 0; k < 9; ++k) fp[k] = e[k] * inv;
  }
  __syncthreads();
  // corner table: 64 pos x 9 taps = 576 tasks over 128 threads, 5 rounds
#pragma unroll
  for (int rr = 0; rr < 5; ++rr) {
    int task = rr * 128 + tid;
    if (task < 576) {
      int p = task / 9;
      int k = task - p * 9;
      const float* fp = fo[p >> 5][p & 31];
      float f = fp[k];
      float dy = fp[9 + 2 * k];
      float dx = fp[10 + 2 * k];
      float ys = (float)(h + (k / 3 - 1) * d) + dy;
      float xs = (float)(p + (k % 3 - 1) * d) + dx;
      float y0f = floorf(ys), x0f = floorf(xs);
      float wy1 = ys - y0f, wx1 = xs - x0f;
      float wy0 = 1.f - wy1, wx0 = 1.f - wx1;
      int y0 = (int)y0f, x0 = (int)x0f;
      int4 ent;
      int* ep = (int*)&ent;
#pragma unroll
      for (int cy = 0; cy < 2; ++cy)
#pragma unroll
        for (int cx = 0; cx < 2; ++cx) {
          int yy = y0 + cy, xx = x0 + cx;
          bool v = ((unsigned)yy < 64u) && ((unsigned)xx < 64u);
          float wt = f * (cy ? wy1 : wy0) * (cx ? wx1 : wx0);
          int row = v ? (yy * 64 + xx) : 0;
          unsigned wb = v ? (unsigned)(unsigned short)f2bf(wt) : 0u;
          ep[cy * 2 + cx] = row | (int)(wb << 16);
        }
      int mm = rowb + (h << 6) + p;
      ((int4*)ctab)[((size_t)di * 8192 + mm) * 9 + k] = ent;
    }
  }
}

// ---- deform bilinear sample from precomputed corner table (R10/R12 form:
// one position per wave — measured local optimum; channel-split (R15) was
// 20% WORSE: two discontiguous 512B segments/instr + 2x ctab reads).
__global__ __launch_bounds__(256, 4) void k_samp(const short* __restrict__ xsrc,
                                                 short* __restrict__ cat,
                                                 const int* __restrict__ ctab) {
  int tid = threadIdx.x;
  int wv = __builtin_amdgcn_readfirstlane(tid >> 6);
  int lane = tid & 63;
  int b = blockIdx.x;
  int di = b >> 11;
  int loc = b & 2047;
  int m = (loc & 7) * 1024 + (loc >> 3) * 4 + wv;  // xcd*1024 + slab*4 + wave
  int n = m >> 12;
  const int4* tp = (const int4*)ctab + ((size_t)di * 8192 + m) * 9;
  const short* xb = xsrc + (size_t)(n << 12) * CST + lane * 8;
  float acc[8] = {0.f, 0.f, 0.f, 0.f, 0.f, 0.f, 0.f, 0.f};
#pragma unroll
  for (int k = 0; k < 9; ++k) {
    int4 e = tp[k];
    const int* ep = (const int*)&e;
#pragma unroll
    for (int c = 0; c < 4; ++c) {
      int dw = ep[c];
      float wt = __builtin_bit_cast(float, (unsigned)dw & 0xFFFF0000u);
      int row = dw & 0xFFFF;
      const short8 vv = *(const short8*)(xb + (size_t)row * CST);
#pragma unroll
      for (int j = 0; j < 8; ++j) acc[j] += wt * bf2f(vv[j]);
    }
  }
  short8 o8;
#pragma unroll
  for (int j = 0; j < 8; ++j) o8[j] = f2bf(acc[j]);
  *(short8*)(cat + (size_t)m * CST + 512 * (di + 1) + lane * 8) = o8;
}

// ---- 1x1 fuse conv, R23 = R18 staging (A+B in LDS via gl16 — B-direct
// was 75us twice, dead) + TRI-buffer, ONE barrier per K-tile.
// FULL-K, BM=BN=128, BK=64, 512 thr = 8 waves (2M x 4N, 64x32/wave),
// grid 256 = 1/CU. LDS 3 x 32KB = 97KB (1 block/CU), T2 swizzle.
// Stage t+2 -> buf[(t+2)%3] right AFTER the top barrier: buf[(t+2)%3] =
// buf[(t-1)%3], whose reads all finished before this barrier (each wave's
// lgkmcnt(0) precedes its t-1 MFMAs) -> R18's 2nd barrier is redundant.
// vmcnt queue/thread = [t(4), t+1(4)] at top -> vmcnt(4); 0 only at t=47.
// Epilogue: final f32 acc -> Y bf16 + fused per-channel stats.
__global__ __launch_bounds__(512, 2) void k_gemm(const short* __restrict__ A,
                                                 const short* __restrict__ B,
                                                 short* __restrict__ Y,
                                                 float* __restrict__ stats) {
  __shared__ short As[3 * 128 * 64];   // 48 KB A tri-buffer
  __shared__ short Bs[3 * 128 * 64];   // 48 KB B tri-buffer
  __shared__ float sred[128][2];       // 1 KB per-col {sum, sumsq}
  int tid = threadIdx.x;
  int wave = tid >> 6, lane = tid & 63;
  int l15 = lane & 15, quad = lane >> 4;
  int bid = blockIdx.x;              // 0..255
  int xcd = bid & 7, g = bid >> 3;   // per-XCD: 8 mt x 4 nt (A reused in L2)
  int mt = xcd * 8 + (g & 7);
  int nt = g >> 3;                   // 0..3
  int m0 = mt * 128, n0 = nt * 128;
  int wm = (wave >> 2) * 64;         // {0,64}
  int wn = (wave & 3) * 32;          // {0,32,64,96}
  f32x4 acc[4][2];
  f32x4 zz = {0.f, 0.f, 0.f, 0.f};
#pragma unroll
  for (int i = 0; i < 4; ++i)
#pragma unroll
    for (int j = 0; j < 2; ++j) acc[i][j] = zz;
  // staging: chunk q = u*512 + tid; row = u*64 + (tid>>3), c8 = tid&7;
  // source col-chunk pre-swizzled (c8 ^ row&7) so LDS dest stays linear.
  int r6 = tid >> 3, c8 = tid & 7;
  int cs = (c8 ^ (r6 & 7)) * 8;
  const short* asrc = A + (size_t)(m0 + r6) * CST + cs;
  const short* bsrc = B + (size_t)(n0 + r6) * CST + cs;
  short* adst = As + tid * 8;
  short* bdst = Bs + tid * 8;
#define STAGE(p, kc)                                                  \
  gl16(asrc + (kc), adst + (p) * 8192);                               \
  gl16(asrc + (size_t)64 * CST + (kc), adst + (p) * 8192 + 4096);     \
  gl16(bsrc + (kc), bdst + (p) * 8192);                               \
  gl16(bsrc + (size_t)64 * CST + (kc), bdst + (p) * 8192 + 4096);
  // prologue: tiles 0 -> buf0, 1 -> buf1 (4 gl16/thread each)
  STAGE(0, 0)
  STAGE(1, 64)
  int cur = 0, sb = 2;               // cur = t%3, sb = (t+2)%3
#pragma unroll 1
  for (int t = 0; t < 48; ++t) {
    if (t == 47) { asm volatile("s_waitcnt vmcnt(0)" ::: "memory"); }
    else         { asm volatile("s_waitcnt vmcnt(4)" ::: "memory"); }
    __builtin_amdgcn_s_barrier();      // tile t resident in buf[cur]
    __builtin_amdgcn_sched_barrier(0);
    if (t < 46) { STAGE(sb, (t + 2) * 64) }   // into buf[(t-1)%3] (free)
    const short* Ab = As + cur * 8192;
    const short* Bb = Bs + cur * 8192;
    short8 a[4][2], bf[2][2];
#pragma unroll
    for (int i = 0; i < 4; ++i) {
      int row = wm + i * 16 + l15;
      const short* rp = Ab + row * 64;
#pragma unroll
      for (int kk = 0; kk < 2; ++kk)
        a[i][kk] = *(const short8*)(rp + ((quad + kk * 4) ^ (row & 7)) * 8);
    }
#pragma unroll
    for (int j = 0; j < 2; ++j) {
      int row = wn + j * 16 + l15;
      const short* rp = Bb + row * 64;
#pragma unroll
      for (int kk = 0; kk < 2; ++kk)
        bf[j][kk] = *(const short8*)(rp + ((quad + kk * 4) ^ (row & 7)) * 8);
    }
    asm volatile("s_waitcnt lgkmcnt(0)" ::: "memory");
    __builtin_amdgcn_sched_barrier(0);
    __builtin_amdgcn_s_setprio(1);
#pragma unroll
    for (int kk = 0; kk < 2; ++kk)
#pragma unroll
      for (int i = 0; i < 4; ++i)
#pragma unroll
        for (int j = 0; j < 2; ++j)
          acc[i][j] = __builtin_amdgcn_mfma_f32_16x16x32_bf16(a[i][kk], bf[j][kk], acc[i][j], 0, 0, 0);
    __builtin_amdgcn_s_setprio(0);
    cur = (cur == 2) ? 0 : cur + 1;
    sb = (sb == 2) ? 0 : sb + 1;
  }
#undef STAGE
  // epilogue: Y write (bf16) + in-block per-channel sum/sumsq reduction
  __syncthreads();
  if (tid < 256) ((float*)sred)[tid] = 0.f;
  __syncthreads();
#pragma unroll
  for (int i = 0; i < 4; ++i) {
    int row = m0 + wm + i * 16 + quad * 4;
#pragma unroll
    for (int j = 0; j < 2; ++j) {
      int col = n0 + wn + j * 16 + l15;
#pragma unroll
      for (int r = 0; r < 4; ++r)
        Y[(size_t)(row + r) * 512 + col] = f2bf(acc[i][j][r]);
    }
  }
#pragma unroll
  for (int j = 0; j < 2; ++j) {
    float s = 0.f, q = 0.f;
#pragma unroll
    for (int i = 0; i < 4; ++i)
#pragma unroll
      for (int r = 0; r < 4; ++r) {
        float v = acc[i][j][r];
        s += v; q += v * v;
      }
    int lc = wn + j * 16 + l15;
    atomicAdd(&sred[lc][0], s);
    atomicAdd(&sred[lc][1], q);
  }
  __syncthreads();
  if (tid < 128) {
    atomicAdd(&stats[n0 + tid], sred[tid][0]);
    atomicAdd(&stats[512 + n0 + tid], sred[tid][1]);
  }
}

// ---- normalize Y + NHWC->NCHW transpose -> d_out. short8 loads
// (8 ch/thread), float4 stores along w, scale applied at store.
__global__ __launch_bounds__(256) void k_norm(const short* __restrict__ Y,
                                              const float* __restrict__ stats,
                                              const float* __restrict__ gamma,
                                              const float* __restrict__ beta,
                                              float* __restrict__ out) {
  __shared__ float tile[64][65];
  int b = blockIdx.x;
  int cblk = b & 7, h = (b >> 3) & 63, n = b >> 9;
  int c0 = cblk * 64;
  int t = threadIdx.x;
  size_t mbase = ((size_t)n * 64 + h) * 64;
  int c8 = t & 7, wq = t >> 3;
#pragma unroll
  for (int it = 0; it < 2; ++it) {
    int w = wq + it * 32;
    size_t ro = (mbase + w) * 512 + c0 + c8 * 8;
    short8 a = *(const short8*)(Y + ro);
#pragma unroll
    for (int j = 0; j < 8; ++j) tile[w][c8 * 8 + j] = bf2f(a[j]);
  }
  __syncthreads();
  int w4 = (t & 15) * 4, cg = t >> 4;
  float* op = out + (((size_t)n * 512 + c0) * 64 + h) * 64;
#pragma unroll
  for (int i = 0; i < 4; ++i) {
    int c2 = cg * 4 + i;
    int cc = c0 + c2;
    float mean = stats[cc] * (1.f / 8192.f);
    float var = stats[512 + cc] * (1.f / 8192.f) - mean * mean;
    float Ai = gamma[cc] * rsqrtf(var + 1e-5f);
    float Bi = beta[cc] - mean * Ai;
    float4 o;
    o.x = tile[w4 + 0][c2] * Ai + Bi;
    o.y = tile[w4 + 1][c2] * Ai + Bi;
    o.z = tile[w4 + 2][c2] * Ai + Bi;
    o.w = tile[w4 + 3][c2] * Ai + Bi;
    *(float4*)(op + (size_t)c2 * 4096 + w4) = o;
  }
}

extern "C" void kernel_launch(void* const* d_in, const int* in_sizes, int n_in,
                              void* d_out, int out_size, void* d_ws, size_t ws_size,
                              hipStream_t stream) {
  const float* x  = (const float*)d_in[0];
  const float* w1 = (const float*)d_in[1];
  const float* w2 = (const float*)d_in[2];
  const float* w3 = (const float*)d_in[3];
  const float* w4 = (const float*)d_in[4];
  const float* w5 = (const float*)d_in[5];
  const float* sw = (const float*)d_in[6];
  const float* gamma = (const float*)d_in[7];
  const float* beta  = (const float*)d_in[8];
  float* out = (float*)d_out;

  char* ws = (char*)d_ws;
  // workspace layout (bytes):
  // cat   @ 0        : 8192*3072*2    = 50331648   (bf16, block0 = x NHWC)
  // wbf   @ 50331648 : 512*3072*2     = 3145728
  // wdr   @ 53477376 : 5*9*32*512*2   = 1474560
  // yb    @ 54951936 : 8192*512*2     = 8388608    (single bf16 full-K Y)
  // stats @ 71729152 : 1024*4         = 4096
  // ctab  @ 71733248 : 40960*36*4     = 5898240    (corner table)
  short* cat   = (short*)ws;
  short* wbf   = (short*)(ws + 50331648);
  short* wdr   = (short*)(ws + 53477376);
  short* yb    = (short*)(ws + 54951936);
  float* stats = (float*)(ws + 71729152);
  int*   ctab  = (int*)(ws + 71733248);

  k_init<<<4676, 256, 0, stream>>>(x, sw, w1, w2, w3, w4, w5, cat, wbf, wdr, stats);
  k_conv<<<640, 128, 0, stream>>>(cat, wdr, ctab);
  k_samp<<<10240, 256, 0, stream>>>(cat, cat, ctab);
  k_gemm<<<256, 512, 0, stream>>>(cat, wbf, yb, stats);
  k_norm<<<1024, 256, 0, stream>>>(yb, stats, gamma, beta, out);
}

// Round 10
// 206.078 us; speedup vs baseline: 1.1600x; 1.0384x over previous
//
#include <hip/hip_runtime.h>

typedef short short8 __attribute__((ext_vector_type(8)));
typedef float f32x4 __attribute__((ext_vector_type(4)));

#define CST 3072  // cat row stride (6*512 channels)

__device__ __forceinline__ float bf2f(short s) {
  unsigned u = ((unsigned)(unsigned short)s) << 16;
  return __builtin_bit_cast(float, u);
}
__device__ __forceinline__ short f2bf(float f) {
  unsigned u = __builtin_bit_cast(unsigned, f);
  u = (u + 0x7FFFu + ((u >> 16) & 1u)) >> 16;
  return (short)u;
}
__device__ __forceinline__ void gl16(const short* g, short* l) {
  __builtin_amdgcn_global_load_lds(
      (const __attribute__((address_space(1))) unsigned*)g,
      (__attribute__((address_space(3))) unsigned*)l, 16, 0, 0);
}

// ---- merged init: blocks <1024 do NCHW->NHWC bf16 transpose of x
// (vectorized short8 stores); blocks 1024..1791 scale_w->bf16 (8 elem/thr);
// 1792..4671 wdr reorder; 4672..4675 stats zero.
__global__ __launch_bounds__(256) void k_init(const float* __restrict__ x,
                                              const float* __restrict__ sw,
                                              const float* __restrict__ w1, const float* __restrict__ w2,
                                              const float* __restrict__ w3, const float* __restrict__ w4,
                                              const float* __restrict__ w5,
                                              short* __restrict__ cat,
                                              short* __restrict__ wbf, short* __restrict__ wdr,
                                              float* __restrict__ stats) {
  __shared__ float tile[64][65];
  int b = blockIdx.x;
  int t = threadIdx.x;
  if (b < 1024) {
    int cblk = b & 7, h = (b >> 3) & 63, n = b >> 9;
    int c0 = cblk * 64;
    int lw = t & 63, grp = t >> 6;
    const float* xp = x + (((size_t)n * 512 + c0) * 64 + h) * 64;
#pragma unroll
    for (int i = 0; i < 16; ++i) {
      int cl = grp * 16 + i;
      tile[cl][lw] = xp[(size_t)cl * 4096 + lw];
    }
    __syncthreads();
    // store: thread -> (channel octet c8 = t&7, w = t>>3 (+32)); short8 writes
    int c8 = t & 7, wq = t >> 3;
    size_t mbase = ((size_t)n * 64 + h) * 64;
#pragma unroll
    for (int it = 0; it < 2; ++it) {
      int w = wq + it * 32;
      short8 o;
#pragma unroll
      for (int j = 0; j < 8; ++j) o[j] = f2bf(tile[c8 * 8 + j][w]);
      *(short8*)(cat + (mbase + w) * CST + c0 + c8 * 8) = o;
    }
  } else if (b < 1792) {
    // scale_w -> bf16, 8 elements per thread
    int i8 = (b - 1024) * 256 + t;
    const float4* sp = (const float4*)(sw + (size_t)i8 * 8);
    float4 f0 = sp[0], f1 = sp[1];
    short8 o;
    o[0] = f2bf(f0.x); o[1] = f2bf(f0.y); o[2] = f2bf(f0.z); o[3] = f2bf(f0.w);
    o[4] = f2bf(f1.x); o[5] = f2bf(f1.y); o[6] = f2bf(f1.z); o[7] = f2bf(f1.w);
    *(short8*)(wbf + (size_t)i8 * 8) = o;
  } else if (b < 4672) {
    int j = (b - 1792) * 256 + t;
    int c = j & 511;
    int t2 = j >> 9;
    int oc = t2 & 31;
    int t3 = t2 >> 5;
    int tap = t3 % 9;
    int di = t3 / 9;
    float v = 0.f;
    if (oc < 27) {
      const float* wp = (di == 0) ? w1 : (di == 1) ? w2 : (di == 2) ? w3 : (di == 3) ? w4 : w5;
      v = wp[((oc * 512 + c) * 3 + tap / 3) * 3 + tap % 3];
    }
    wdr[j] = f2bf(v);
  } else {
    int idx = (b - 4672) * 256 + t;
    stats[idx] = 0.f;
  }
}

// ---- offset conv + softmax + corner-table build. [R4 form — measured best]
// Block = 128 thr (2 waves) = one image row (n,h): 64 positions.
// Wave covers 32 positions (2 m-tiles sharing B-frags): 2 b128/pos/tap.
// K split in halves (kh): LDS = A 32 KB + B 16 KB = 48 KB -> 3 blocks/CU
// (fo buffer aliases As: written only after all MFMA reads, extra barrier).
// Swizzle: LDS slot (row,ch) holds source chunk ch^(row&7).
// C/D layout: row (m=position) = quad*4+reg, col (n=oc) = l15.
__global__ __launch_bounds__(128) void k_conv(const short* __restrict__ xsrc,
                                              const short* __restrict__ wdr_all,
                                              int* __restrict__ ctab) {
  __shared__ short As[64 * 256];   // 32 KB: 64 cols x 256 ch (kh half)
  __shared__ short Bs[32 * 256];   // 16 KB: 32 oc x 256 ch
  float (*fo)[32][33] = (float (*)[32][33])(void*)As;  // aliased: used post-MFMA
  int tid = threadIdx.x;
  int wave = tid >> 6, lane = tid & 63;
  int l15 = lane & 15, quad = lane >> 4;
  int b = blockIdx.x;
  int di = b >> 7;
  int loc = b & 127;
  const int DIL[5] = {1, 6, 12, 24, 36};
  int d = DIL[di];
  int rid = (loc & 7) * 16 + (loc >> 3);  // xcd-affine row id (0..127)
  int h = rid & 63, n = rid >> 6;         // block-uniform row
  f32x4 acc[2][2];
  f32x4 zz = {0.f, 0.f, 0.f, 0.f};
#pragma unroll
  for (int i = 0; i < 2; ++i)
#pragma unroll
    for (int j = 0; j < 2; ++j) acc[i][j] = zz;
  const short8 z8 = {0, 0, 0, 0, 0, 0, 0, 0};
  // per-lane staging source offsets (slot q = i*128 + tid)
  int aoff[16];
  int boff[8];
#pragma unroll
  for (int i = 0; i < 16; ++i) {
    int q = i * 128 + tid;
    int w = q >> 5, ch = q & 31;
    aoff[i] = w * CST + (ch ^ (w & 7)) * 8;
  }
#pragma unroll
  for (int i = 0; i < 8; ++i) {
    int q = i * 128 + tid;
    int oc = q >> 5, ch = q & 31;
    boff[i] = oc * 512 + (ch ^ (oc & 7)) * 8;
  }
  const short* wbase = wdr_all + (size_t)di * 9 * 32 * 512;
  int rowb = (n << 12);
#pragma unroll 1
  for (int kh = 0; kh < 2; ++kh) {
    int lastty = -1;
#pragma unroll
    for (int tap = 0; tap < 9; ++tap) {
      int ty = tap / 3, tx = tap % 3;
      int hh = h + (ty - 1) * d;
      if ((unsigned)hh >= 64u) continue;   // block-uniform skip
      __syncthreads();                     // prior LDS reads complete
      if (ty != lastty) {                  // stage full row hh (A), kh half
        const short* abase = xsrc + (size_t)(rowb + (hh << 6)) * CST + kh * 256;
#pragma unroll
        for (int i = 0; i < 16; ++i)
          gl16(abase + aoff[i], As + (i * 128 + wave * 64) * 8);
        lastty = ty;
      }
      {                                    // stage B tap, kh half
        const short* bbase = wbase + tap * 32 * 512 + kh * 256;
#pragma unroll
        for (int i = 0; i < 8; ++i)
          gl16(bbase + boff[i], Bs + (i * 128 + wave * 64) * 8);
      }
      __syncthreads();                     // gl16 drained
      int s0 = wave * 32 + (tx - 1) * d;   // col of (mt,l15): s0 + mt*16 + l15
#pragma unroll
      for (int ks = 0; ks < 8; ++ks) {
        int c = ks * 4 + quad;
        short8 a[2], bb[2];
#pragma unroll
        for (int mt = 0; mt < 2; ++mt) {
          int wp = s0 + mt * 16 + l15;
          bool ok = (unsigned)wp < 64u;
          int wc = ok ? wp : 0;
          short8 av = *(const short8*)(As + wc * 256 + (c ^ (wc & 7)) * 8);
          a[mt] = ok ? av : z8;
        }
#pragma unroll
        for (int ot = 0; ot < 2; ++ot) {
          int oc = ot * 16 + l15;
          bb[ot] = *(const short8*)(Bs + oc * 256 + (c ^ (oc & 7)) * 8);
        }
#pragma unroll
        for (int mt = 0; mt < 2; ++mt)
#pragma unroll
          for (int ot = 0; ot < 2; ++ot)
            acc[mt][ot] = __builtin_amdgcn_mfma_f32_16x16x32_bf16(a[mt], bb[ot], acc[mt][ot], 0, 0, 0);
      }
    }
  }
  __syncthreads();   // all waves done reading As before fo (aliased) is written
  // write fo: C row (quad*4+r) = position, C col (l15) = oc
#pragma unroll
  for (int mt = 0; mt < 2; ++mt)
#pragma unroll
    for (int ot = 0; ot < 2; ++ot)
#pragma unroll
      for (int r = 0; r < 4; ++r)
        fo[wave][mt * 16 + quad * 4 + r][ot * 16 + l15] = acc[mt][ot][r];
  __syncthreads();
  if (tid < 64) {   // softmax: one position per thread (wave0)
    int p = tid;
    float* fp = fo[p >> 5][p & 31];
    float mx = fp[0];
#pragma unroll
    for (int k = 1; k < 9; ++k) mx = fmaxf(mx, fp[k]);
    float s = 0.f, e[9];
#pragma unroll
    for (int k = 0; k < 9; ++k) { e[k] = __expf(fp[k] - mx); s += e[k]; }
    float inv = 1.f / s;
#pragma unroll
    for (int k = 0; k < 9; ++k) fp[k] = e[k] * inv;
  }
  __syncthreads();
  // corner table: 64 pos x 9 taps = 576 tasks over 128 threads, 5 rounds
#pragma unroll
  for (int rr = 0; rr < 5; ++rr) {
    int task = rr * 128 + tid;
    if (task < 576) {
      int p = task / 9;
      int k = task - p * 9;
      const float* fp = fo[p >> 5][p & 31];
      float f = fp[k];
      float dy = fp[9 + 2 * k];
      float dx = fp[10 + 2 * k];
      float ys = (float)(h + (k / 3 - 1) * d) + dy;
      float xs = (float)(p + (k % 3 - 1) * d) + dx;
      float y0f = floorf(ys), x0f = floorf(xs);
      float wy1 = ys - y0f, wx1 = xs - x0f;
      float wy0 = 1.f - wy1, wx0 = 1.f - wx1;
      int y0 = (int)y0f, x0 = (int)x0f;
      int4 ent;
      int* ep = (int*)&ent;
#pragma unroll
      for (int cy = 0; cy < 2; ++cy)
#pragma unroll
        for (int cx = 0; cx < 2; ++cx) {
          int yy = y0 + cy, xx = x0 + cx;
          bool v = ((unsigned)yy < 64u) && ((unsigned)xx < 64u);
          float wt = f * (cy ? wy1 : wy0) * (cx ? wx1 : wx0);
          int row = v ? (yy * 64 + xx) : 0;
          unsigned wb = v ? (unsigned)(unsigned short)f2bf(wt) : 0u;
          ep[cy * 2 + cx] = row | (int)(wb << 16);
        }
      int mm = rowb + (h << 6) + p;
      ((int4*)ctab)[((size_t)di * 8192 + mm) * 9 + k] = ent;
    }
  }
}

// ---- deform bilinear sample from precomputed corner table (R10/R12 form:
// one position per wave — measured local optimum; channel-split (R15) was
// 20% WORSE: two discontiguous 512B segments/instr + 2x ctab reads).
__global__ __launch_bounds__(256, 4) void k_samp(const short* __restrict__ xsrc,
                                                 short* __restrict__ cat,
                                                 const int* __restrict__ ctab) {
  int tid = threadIdx.x;
  int wv = __builtin_amdgcn_readfirstlane(tid >> 6);
  int lane = tid & 63;
  int b = blockIdx.x;
  int di = b >> 11;
  int loc = b & 2047;
  int m = (loc & 7) * 1024 + (loc >> 3) * 4 + wv;  // xcd*1024 + slab*4 + wave
  int n = m >> 12;
  const int4* tp = (const int4*)ctab + ((size_t)di * 8192 + m) * 9;
  const short* xb = xsrc + (size_t)(n << 12) * CST + lane * 8;
  float acc[8] = {0.f, 0.f, 0.f, 0.f, 0.f, 0.f, 0.f, 0.f};
#pragma unroll
  for (int k = 0; k < 9; ++k) {
    int4 e = tp[k];
    const int* ep = (const int*)&e;
#pragma unroll
    for (int c = 0; c < 4; ++c) {
      int dw = ep[c];
      float wt = __builtin_bit_cast(float, (unsigned)dw & 0xFFFF0000u);
      int row = dw & 0xFFFF;
      const short8 vv = *(const short8*)(xb + (size_t)row * CST);
#pragma unroll
      for (int j = 0; j < 8; ++j) acc[j] += wt * bf2f(vv[j]);
    }
  }
  short8 o8;
#pragma unroll
  for (int j = 0; j < 8; ++j) o8[j] = f2bf(acc[j]);
  *(short8*)(cat + (size_t)m * CST + 512 * (di + 1) + lane * 8) = o8;
}

// ---- 1x1 fuse conv, R18 form (measured best across R16/R19/R21/R22/R23
// variants): FULL-K, BM=BN=128, BK=64, 512 thr = 8 waves (2M x 4N,
// per-wave 64x32), grid 256 = 1/CU. LDS 64 KB dbuf, T2 swizzle, counted
// vmcnt(4), prefetch dist 2. Epilogue: final f32 acc -> Y bf16 + fused
// per-channel stats reduction (k_stats eliminated).
__global__ __launch_bounds__(512, 2) void k_gemm(const short* __restrict__ A,
                                                 const short* __restrict__ B,
                                                 short* __restrict__ Y,
                                                 float* __restrict__ stats) {
  __shared__ short As[2][128 * 64];   // 32 KB
  __shared__ short Bs[2][128 * 64];   // 32 KB
  __shared__ float sred[128][2];      // 1 KB: per-col {sum, sumsq}
  int tid = threadIdx.x;
  int wave = tid >> 6, lane = tid & 63;
  int l15 = lane & 15, quad = lane >> 4;
  int bid = blockIdx.x;              // 0..255
  int xcd = bid & 7, g = bid >> 3;   // per-XCD: 8 mt x 4 nt (A reused 4x in L2)
  int mt = xcd * 8 + (g & 7);
  int nt = g >> 3;                   // 0..3
  int m0 = mt * 128, n0 = nt * 128;
  int wm = (wave >> 2) * 64;         // {0,64}
  int wn = (wave & 3) * 32;          // {0,32,64,96}
  f32x4 acc[4][2];
  f32x4 zz = {0.f, 0.f, 0.f, 0.f};
#pragma unroll
  for (int i = 0; i < 4; ++i)
#pragma unroll
    for (int j = 0; j < 2; ++j) acc[i][j] = zz;
  // staging: chunk q = u*512 + tid; row = u*64 + (tid>>3), c8 = tid&7;
  // source col-chunk pre-swizzled (c8 ^ row&7) so LDS dest stays linear.
  int r6 = tid >> 3, c8 = tid & 7;
  int cs = (c8 ^ (r6 & 7)) * 8;
  const short* asrc = A + (size_t)(m0 + r6) * CST + cs;
  const short* bsrc = B + (size_t)(n0 + r6) * CST + cs;
  short* adst = &As[0][0] + tid * 8;
  short* bdst = &Bs[0][0] + tid * 8;
#define STAGE_A(p, u, kc) gl16(asrc + (size_t)(u) * 64 * CST + (kc), adst + (p) * 8192 + (u) * 4096)
#define STAGE_B(p, u, kc) gl16(bsrc + (size_t)(u) * 64 * CST + (kc), bdst + (p) * 8192 + (u) * 4096)
  // prologue: K-tiles 0 and 1 (4 gl16 each; order matters for vmcnt)
  STAGE_A(0, 0, 0); STAGE_A(0, 1, 0); STAGE_B(0, 0, 0); STAGE_B(0, 1, 0);
  STAGE_A(1, 0, 64); STAGE_A(1, 1, 64); STAGE_B(1, 0, 64); STAGE_B(1, 1, 64);
#pragma unroll 1
  for (int t = 0; t < 48; ++t) {
    int cur = t & 1;
    if (t == 47) { asm volatile("s_waitcnt vmcnt(0)" ::: "memory"); }
    else         { asm volatile("s_waitcnt vmcnt(4)" ::: "memory"); }
    __builtin_amdgcn_s_barrier();      // tile t resident in buf[cur]
    __builtin_amdgcn_sched_barrier(0);
    const short* Ab = &As[cur][0];
    const short* Bb = &Bs[cur][0];
    short8 a[4][2], bf[2][2];
#pragma unroll
    for (int i = 0; i < 4; ++i) {
      int row = wm + i * 16 + l15;
      const short* rp = Ab + row * 64;
#pragma unroll
      for (int kk = 0; kk < 2; ++kk)
        a[i][kk] = *(const short8*)(rp + ((quad + kk * 4) ^ (row & 7)) * 8);
    }
#pragma unroll
    for (int j = 0; j < 2; ++j) {
      int row = wn + j * 16 + l15;
      const short* rp = Bb + row * 64;
#pragma unroll
      for (int kk = 0; kk < 2; ++kk)
        bf[j][kk] = *(const short8*)(rp + ((quad + kk * 4) ^ (row & 7)) * 8);
    }
    asm volatile("s_waitcnt lgkmcnt(0)" ::: "memory");
    __builtin_amdgcn_sched_barrier(0);
    __builtin_amdgcn_s_barrier();      // all waves' reads done -> buffer free
    __builtin_amdgcn_sched_barrier(0);
    if (t < 46) {                      // stage tile t+2 into buf[cur]
      int kc = (t + 2) * 64;
      STAGE_A(cur, 0, kc); STAGE_A(cur, 1, kc);
      STAGE_B(cur, 0, kc); STAGE_B(cur, 1, kc);
    }
    __builtin_amdgcn_s_setprio(1);
#pragma unroll
    for (int kk = 0; kk < 2; ++kk)
#pragma unroll
      for (int i = 0; i < 4; ++i)
#pragma unroll
        for (int j = 0; j < 2; ++j)
          acc[i][j] = __builtin_amdgcn_mfma_f32_16x16x32_bf16(a[i][kk], bf[j][kk], acc[i][j], 0, 0, 0);
    __builtin_amdgcn_s_setprio(0);
  }
#undef STAGE_A
#undef STAGE_B
  // epilogue: Y write (bf16) + in-block per-channel sum/sumsq reduction
  if (tid < 256) ((float*)sred)[tid] = 0.f;
  __syncthreads();
#pragma unroll
  for (int i = 0; i < 4; ++i) {
    int row = m0 + wm + i * 16 + quad * 4;
#pragma unroll
    for (int j = 0; j < 2; ++j) {
      int col = n0 + wn + j * 16 + l15;
#pragma unroll
      for (int r = 0; r < 4; ++r)
        Y[(size_t)(row + r) * 512 + col] = f2bf(acc[i][j][r]);
    }
  }
#pragma unroll
  for (int j = 0; j < 2; ++j) {
    float s = 0.f, q = 0.f;
#pragma unroll
    for (int i = 0; i < 4; ++i)
#pragma unroll
      for (int r = 0; r < 4; ++r) {
        float v = acc[i][j][r];
        s += v; q += v * v;
      }
    int lc = wn + j * 16 + l15;
    atomicAdd(&sred[lc][0], s);
    atomicAdd(&sred[lc][1], q);
  }
  __syncthreads();
  if (tid < 128) {
    atomicAdd(&stats[n0 + tid], sred[tid][0]);
    atomicAdd(&stats[512 + n0 + tid], sred[tid][1]);
  }
}

// ---- normalize Y + NHWC->NCHW transpose -> d_out. short8 loads
// (8 ch/thread), float4 stores along w, scale applied at store.
__global__ __launch_bounds__(256) void k_norm(const short* __restrict__ Y,
                                              const float* __restrict__ stats,
                                              const float* __restrict__ gamma,
                                              const float* __restrict__ beta,
                                              float* __restrict__ out) {
  __shared__ float tile[64][65];
  int b = blockIdx.x;
  int cblk = b & 7, h = (b >> 3) & 63, n = b >> 9;
  int c0 = cblk * 64;
  int t = threadIdx.x;
  size_t mbase = ((size_t)n * 64 + h) * 64;
  int c8 = t & 7, wq = t >> 3;
#pragma unroll
  for (int it = 0; it < 2; ++it) {
    int w = wq + it * 32;
    size_t ro = (mbase + w) * 512 + c0 + c8 * 8;
    short8 a = *(const short8*)(Y + ro);
#pragma unroll
    for (int j = 0; j < 8; ++j) tile[w][c8 * 8 + j] = bf2f(a[j]);
  }
  __syncthreads();
  int w4 = (t & 15) * 4, cg = t >> 4;
  float* op = out + (((size_t)n * 512 + c0) * 64 + h) * 64;
#pragma unroll
  for (int i = 0; i < 4; ++i) {
    int c2 = cg * 4 + i;
    int cc = c0 + c2;
    float mean = stats[cc] * (1.f / 8192.f);
    float var = stats[512 + cc] * (1.f / 8192.f) - mean * mean;
    float Ai = gamma[cc] * rsqrtf(var + 1e-5f);
    float Bi = beta[cc] - mean * Ai;
    float4 o;
    o.x = tile[w4 + 0][c2] * Ai + Bi;
    o.y = tile[w4 + 1][c2] * Ai + Bi;
    o.z = tile[w4 + 2][c2] * Ai + Bi;
    o.w = tile[w4 + 3][c2] * Ai + Bi;
    *(float4*)(op + (size_t)c2 * 4096 + w4) = o;
  }
}

extern "C" void kernel_launch(void* const* d_in, const int* in_sizes, int n_in,
                              void* d_out, int out_size, void* d_ws, size_t ws_size,
                              hipStream_t stream) {
  const float* x  = (const float*)d_in[0];
  const float* w1 = (const float*)d_in[1];
  const float* w2 = (const float*)d_in[2];
  const float* w3 = (const float*)d_in[3];
  const float* w4 = (const float*)d_in[4];
  const float* w5 = (const float*)d_in[5];
  const float* sw = (const float*)d_in[6];
  const float* gamma = (const float*)d_in[7];
  const float* beta  = (const float*)d_in[8];
  float* out = (float*)d_out;

  char* ws = (char*)d_ws;
  // workspace layout (bytes):
  // cat   @ 0        : 8192*3072*2    = 50331648   (bf16, block0 = x NHWC)
  // wbf   @ 50331648 : 512*3072*2     = 3145728
  // wdr   @ 53477376 : 5*9*32*512*2   = 1474560
  // yb    @ 54951936 : 8192*512*2     = 8388608    (single bf16 full-K Y)
  // stats @ 71729152 : 1024*4         = 4096
  // ctab  @ 71733248 : 40960*36*4     = 5898240    (corner table)
  short* cat   = (short*)ws;
  short* wbf   = (short*)(ws + 50331648);
  short* wdr   = (short*)(ws + 53477376);
  short* yb    = (short*)(ws + 54951936);
  float* stats = (float*)(ws + 71729152);
  int*   ctab  = (int*)(ws + 71733248);

  k_init<<<4676, 256, 0, stream>>>(x, sw, w1, w2, w3, w4, w5, cat, wbf, wdr, stats);
  k_conv<<<640, 128, 0, stream>>>(cat, wdr, ctab);
  k_samp<<<10240, 256, 0, stream>>>(cat, cat, ctab);
  k_gemm<<<256, 512, 0, stream>>>(cat, wbf, yb, stats);
  k_norm<<<1024, 256, 0, stream>>>(yb, stats, gamma, beta, out);
}